// Round 1
// baseline (360.965 us; speedup 1.0000x reference)
//
#include <hip/hip_runtime.h>
#include <math.h>

// KNN-attention: N=50000 points, K=16 neighbors, HIDDEN=256 = 8 heads x 32 dim.
// One wave64 per point: lane = head*8 + (d/4); each lane owns a float4 slice.
// 8 lanes/head x 16B = 128B coalesced per gathered key/value row-slice.

#define KNN_K      16
#define HIDDEN_    256
#define HEAD_DIM_  32
#define SCALE_     0.17677669529663687f   // 32^-0.5

__global__ __launch_bounds__(256) void knn_attn_kernel(
    const float* __restrict__ keys,
    const float* __restrict__ queries,
    const float* __restrict__ values,
    const int*   __restrict__ nbr,
    float*       __restrict__ out,
    int n_pts)
{
    const int gtid = blockIdx.x * blockDim.x + threadIdx.x;
    const int pt   = gtid >> 6;            // one wave64 per point
    const int lane = threadIdx.x & 63;
    if (pt >= n_pts) return;

    const int h   = lane >> 3;             // head 0..7
    const int d4  = (lane & 7) << 2;       // float4 slot within head
    const int col = h * HEAD_DIM_ + d4;    // column 0..255 (x4)

    // Each lane loads one neighbor index (lanes 0..15 meaningful), broadcast later.
    const int my_idx = nbr[(size_t)pt * KNN_K + (lane & 15)];

    const float4 q4 = *reinterpret_cast<const float4*>(
        queries + (size_t)pt * HIDDEN_ + col);

    // ---- scores: q . k_nbr over the 32-dim head, reduced across 8 lanes ----
    float s[KNN_K];
    #pragma unroll
    for (int k = 0; k < KNN_K; ++k) {
        const int nk = __shfl(my_idx, k, 64);
        const float4 k4 = *reinterpret_cast<const float4*>(
            keys + (size_t)nk * HIDDEN_ + col);
        float p = q4.x * k4.x + q4.y * k4.y + q4.z * k4.z + q4.w * k4.w;
        p += __shfl_xor(p, 1, 64);   // xor masks 1,2,4 stay inside the
        p += __shfl_xor(p, 2, 64);   // aligned 8-lane head group
        p += __shfl_xor(p, 4, 64);
        s[k] = p * SCALE_;
    }

    // ---- softmax over K=16, fully in registers (every lane has all scores) ----
    float m = s[0];
    #pragma unroll
    for (int k = 1; k < KNN_K; ++k) m = fmaxf(m, s[k]);
    float denom = 0.f;
    #pragma unroll
    for (int k = 0; k < KNN_K; ++k) { s[k] = __expf(s[k] - m); denom += s[k]; }
    const float inv = 1.0f / denom;

    // ---- weighted sum of gathered values ----
    float4 acc = make_float4(0.f, 0.f, 0.f, 0.f);
    #pragma unroll
    for (int k = 0; k < KNN_K; ++k) {
        const int nk = __shfl(my_idx, k, 64);
        const float4 v4 = *reinterpret_cast<const float4*>(
            values + (size_t)nk * HIDDEN_ + col);
        const float w = s[k] * inv;
        acc.x += w * v4.x; acc.y += w * v4.y; acc.z += w * v4.z; acc.w += w * v4.w;
    }

    *reinterpret_cast<float4*>(out + (size_t)pt * HIDDEN_ + col) = acc;
}

extern "C" void kernel_launch(void* const* d_in, const int* in_sizes, int n_in,
                              void* d_out, int out_size, void* d_ws, size_t ws_size,
                              hipStream_t stream) {
    const float* keys    = (const float*)d_in[0];
    const float* queries = (const float*)d_in[1];
    const float* values  = (const float*)d_in[2];
    const int*   nbr     = (const int*)d_in[3];
    float*       out     = (float*)d_out;

    const int n_pts  = in_sizes[3] / KNN_K;      // 50000
    const int waves_per_block = 4;               // 256 threads
    const int blocks = (n_pts + waves_per_block - 1) / waves_per_block;
    knn_attn_kernel<<<blocks, 256, 0, stream>>>(keys, queries, values, nbr, out, n_pts);
}

// Round 3
// 360.563 us; speedup vs baseline: 1.0011x; 1.0011x over previous
//
#include <hip/hip_runtime.h>
#include <math.h>

// KNN-attention: N=50000, K=16 neighbors, HIDDEN=256 = 8 heads x 32 dim.
// One wave64 per point: lane = head*8 + (d/4); each lane owns a float4 slice.
// Round-2 restructure: explicit MLP — all 16 idx via wave-uniform int4 loads,
// then 32 gather loads (16 K + 16 V) issued into registers BEFORE the serial
// shuffle-reduce, so gather latency is hidden by in-flight loads, not waves.

#define KNN_K      16
#define HIDDEN_    256
#define HEAD_DIM_  32
#define SCALE_     0.17677669529663687f   // 32^-0.5

__global__ __launch_bounds__(256) void knn_attn_kernel(
    const float* __restrict__ keys,
    const float* __restrict__ queries,
    const float* __restrict__ values,
    const int*   __restrict__ nbr,
    float*       __restrict__ out,
    int n_pts)
{
    const int gtid = blockIdx.x * blockDim.x + threadIdx.x;
    const int pt   = gtid >> 6;            // one wave64 per point
    const int lane = threadIdx.x & 63;
    if (pt >= n_pts) return;

    const int h   = lane >> 3;             // head 0..7
    const int d4  = (lane & 7) << 2;       // float4 slot within head
    const int col = h * HEAD_DIM_ + d4;    // column 0..255 (x4)

    // All 64 lanes read the SAME 16 indices (wave-uniform address -> one
    // broadcast fetch per int4). No shuffles needed; addresses ready at once.
    const int4* nb4 = reinterpret_cast<const int4*>(nbr + (size_t)pt * KNN_K);
    const int4 i0 = nb4[0], i1 = nb4[1], i2 = nb4[2], i3 = nb4[3];
    const int idx[KNN_K] = { i0.x,i0.y,i0.z,i0.w, i1.x,i1.y,i1.z,i1.w,
                             i2.x,i2.y,i2.z,i2.w, i3.x,i3.y,i3.z,i3.w };

    const float4 q4 = *reinterpret_cast<const float4*>(
        queries + (size_t)pt * HIDDEN_ + col);

    // ---- issue ALL gathers up front: 32 independent loads in flight ----
    float4 kr[KNN_K];
    #pragma unroll
    for (int k = 0; k < KNN_K; ++k)
        kr[k] = *reinterpret_cast<const float4*>(
            keys + (size_t)idx[k] * HIDDEN_ + col);

    float4 vr[KNN_K];
    #pragma unroll
    for (int k = 0; k < KNN_K; ++k)
        vr[k] = *reinterpret_cast<const float4*>(
            values + (size_t)idx[k] * HIDDEN_ + col);

    // ---- scores: per-head dot over 32 dims, reduced across the 8-lane group.
    // The 3-deep shfl chains overlap the V loads still in flight. ----
    float s[KNN_K];
    #pragma unroll
    for (int k = 0; k < KNN_K; ++k) {
        float p = q4.x * kr[k].x + q4.y * kr[k].y
                + q4.z * kr[k].z + q4.w * kr[k].w;
        p += __shfl_xor(p, 1, 64);
        p += __shfl_xor(p, 2, 64);
        p += __shfl_xor(p, 4, 64);
        s[k] = p * SCALE_;
    }

    // ---- softmax over K=16 in registers; normalize once at the end ----
    float m = s[0];
    #pragma unroll
    for (int k = 1; k < KNN_K; ++k) m = fmaxf(m, s[k]);
    float denom = 0.f;
    #pragma unroll
    for (int k = 0; k < KNN_K; ++k) { s[k] = __expf(s[k] - m); denom += s[k]; }
    const float inv = 1.0f / denom;

    float4 acc = make_float4(0.f, 0.f, 0.f, 0.f);
    #pragma unroll
    for (int k = 0; k < KNN_K; ++k) {
        acc.x += s[k] * vr[k].x; acc.y += s[k] * vr[k].y;
        acc.z += s[k] * vr[k].z; acc.w += s[k] * vr[k].w;
    }
    acc.x *= inv; acc.y *= inv; acc.z *= inv; acc.w *= inv;

    *reinterpret_cast<float4*>(out + (size_t)pt * HIDDEN_ + col) = acc;
}

extern "C" void kernel_launch(void* const* d_in, const int* in_sizes, int n_in,
                              void* d_out, int out_size, void* d_ws, size_t ws_size,
                              hipStream_t stream) {
    const float* keys    = (const float*)d_in[0];
    const float* queries = (const float*)d_in[1];
    const float* values  = (const float*)d_in[2];
    const int*   nbr     = (const int*)d_in[3];
    float*       out     = (float*)d_out;

    const int n_pts = in_sizes[3] / KNN_K;       // 50000
    const int waves_per_block = 4;               // 256 threads
    const int blocks = (n_pts + waves_per_block - 1) / waves_per_block;
    knn_attn_kernel<<<blocks, 256, 0, stream>>>(keys, queries, values, nbr, out, n_pts);
}

// Round 5
// 358.282 us; speedup vs baseline: 1.0075x; 1.0064x over previous
//
#include <hip/hip_runtime.h>
#include <math.h>

// KNN-attention: N=50000, K=16 neighbors, HIDDEN=256 = 8 heads x 32 dim.
// One wave64 per point: lane = head*8 + (d/4); each lane owns a float4 slice.
//
// Round-4: rounds 1-3 showed the compiler serializes the 32 gathers (VGPR=56,
// load->use->load chains, ~36k cyc/wave). Force memory-level parallelism with
// __builtin_amdgcn_sched_barrier(0): all 32 gather loads issue BEFORE any
// consumption, so the wave keeps 32 loads in flight (first use waits at
// vmcnt(31), not vmcnt(0)). Trades VGPRs/occupancy for 32x per-wave MLP.

#define KNN_K      16
#define HIDDEN_    256
#define HEAD_DIM_  32
#define SCALE_     0.17677669529663687f   // 32^-0.5

__global__ __launch_bounds__(256) void knn_attn_kernel(
    const float* __restrict__ keys,
    const float* __restrict__ queries,
    const float* __restrict__ values,
    const int*   __restrict__ nbr,
    float*       __restrict__ out,
    int n_pts)
{
    const int gtid = blockIdx.x * blockDim.x + threadIdx.x;
    const int pt   = gtid >> 6;            // one wave64 per point
    const int lane = threadIdx.x & 63;
    if (pt >= n_pts) return;

    const int h   = lane >> 3;             // head 0..7
    const int d4  = (lane & 7) << 2;       // float4 slot within head
    const int col = h * HEAD_DIM_ + d4;    // column 0..255 (x4)

    // Wave-uniform neighbor indices: one broadcast int4 fetch per 4 indices.
    const int4* nb4 = reinterpret_cast<const int4*>(nbr + (size_t)pt * KNN_K);
    const int4 i0 = nb4[0], i1 = nb4[1], i2 = nb4[2], i3 = nb4[3];
    const int idx[KNN_K] = { i0.x,i0.y,i0.z,i0.w, i1.x,i1.y,i1.z,i1.w,
                             i2.x,i2.y,i2.z,i2.w, i3.x,i3.y,i3.z,i3.w };

    const float4 q4 = *reinterpret_cast<const float4*>(
        queries + (size_t)pt * HIDDEN_ + col);

    // ---- issue ALL 32 gathers; fence so nothing sinks them back ----
    float4 kr[KNN_K];
    #pragma unroll
    for (int k = 0; k < KNN_K; ++k)
        kr[k] = *reinterpret_cast<const float4*>(
            keys + (size_t)idx[k] * HIDDEN_ + col);

    float4 vr[KNN_K];
    #pragma unroll
    for (int k = 0; k < KNN_K; ++k)
        vr[k] = *reinterpret_cast<const float4*>(
            values + (size_t)idx[k] * HIDDEN_ + col);

    // Hard scheduling fence: no instruction may cross. All 32 loads are now
    // issued; consumption below waits on counted vmcnt, overlapping latency.
    __builtin_amdgcn_sched_barrier(0);

    // ---- scores: per-head dot over 32 dims, reduced across the 8-lane group.
    float s[KNN_K];
    #pragma unroll
    for (int k = 0; k < KNN_K; ++k) {
        float p = q4.x * kr[k].x + q4.y * kr[k].y
                + q4.z * kr[k].z + q4.w * kr[k].w;
        p += __shfl_xor(p, 1, 64);
        p += __shfl_xor(p, 2, 64);
        p += __shfl_xor(p, 4, 64);
        s[k] = p * SCALE_;
    }

    // ---- softmax over K=16 in registers; normalize once at the end ----
    float m = s[0];
    #pragma unroll
    for (int k = 1; k < KNN_K; ++k) m = fmaxf(m, s[k]);
    float denom = 0.f;
    #pragma unroll
    for (int k = 0; k < KNN_K; ++k) { s[k] = __expf(s[k] - m); denom += s[k]; }
    const float inv = 1.0f / denom;

    float4 acc = make_float4(0.f, 0.f, 0.f, 0.f);
    #pragma unroll
    for (int k = 0; k < KNN_K; ++k) {
        acc.x += s[k] * vr[k].x; acc.y += s[k] * vr[k].y;
        acc.z += s[k] * vr[k].z; acc.w += s[k] * vr[k].w;
    }
    acc.x *= inv; acc.y *= inv; acc.z *= inv; acc.w *= inv;

    *reinterpret_cast<float4*>(out + (size_t)pt * HIDDEN_ + col) = acc;
}

extern "C" void kernel_launch(void* const* d_in, const int* in_sizes, int n_in,
                              void* d_out, int out_size, void* d_ws, size_t ws_size,
                              hipStream_t stream) {
    const float* keys    = (const float*)d_in[0];
    const float* queries = (const float*)d_in[1];
    const float* values  = (const float*)d_in[2];
    const int*   nbr     = (const int*)d_in[3];
    float*       out     = (float*)d_out;

    const int n_pts = in_sizes[3] / KNN_K;       // 50000
    const int waves_per_block = 4;               // 256 threads
    const int blocks = (n_pts + waves_per_block - 1) / waves_per_block;
    knn_attn_kernel<<<blocks, 256, 0, stream>>>(keys, queries, values, nbr, out, n_pts);
}